// Round 4
// baseline (232.765 us; speedup 1.0000x reference)
//
#include <hip/hip_runtime.h>
#include <stdint.h>

typedef unsigned short u16;
typedef __attribute__((ext_vector_type(8))) short bf16x8;
typedef __attribute__((ext_vector_type(4))) float f32x4;

#define MFMA(a,b,c) __builtin_amdgcn_mfma_f32_16x16x32_bf16((a),(b),(c),0,0,0)

static constexpr int S  = 4096;
static constexpr int D  = 768;
static constexpr int H  = 12;
static constexpr int HD = 64;
static constexpr unsigned NUNITS = 24 * 32;   // (bh, qtile) work units

// float -> bf16 round-nearest-even
__device__ __forceinline__ u16 f2b(float f){
  union { float f; unsigned u; } v; v.f = f;
  unsigned r = (v.u + 0x7fffu + ((v.u >> 16) & 1u)) >> 16;
  return (u16)r;
}

// pack 2 floats -> 2 bf16 (truncation) in ONE v_perm_b32
__device__ __forceinline__ unsigned pack_bf16_trunc(float a, float b){
  return __builtin_amdgcn_perm(__float_as_uint(b), __float_as_uint(a), 0x07060302u);
}

// async global->LDS 16B per lane (DMA path, no VGPR round-trip)
__device__ __forceinline__ void cp16(const u16* g, u16* l){
  __builtin_amdgcn_global_load_lds(
      (const __attribute__((address_space(1))) unsigned int*)g,
      (__attribute__((address_space(3))) unsigned int*)l, 16, 0, 0);
}

// 4-lane (quad) butterfly transpose via gfx950 permlane swaps (4 VALU instrs).
// Input M[c]: keys ktL*16 + quad*4 + {0,1 | 2,3} (32-key group) packed 2-bf16/u32.
// Output: bf16x8 P fragment: lane quad holds keys quad*8 .. quad*8+7 in order.
__device__ __forceinline__ bf16x8 quad_transpose(unsigned M0, unsigned M1,
                                                 unsigned M2, unsigned M3){
  auto r0 = __builtin_amdgcn_permlane32_swap(M0, M2, false, false);  // {A0, A2}
  auto r1 = __builtin_amdgcn_permlane32_swap(M1, M3, false, false);  // {A1, A3}
  auto s0 = __builtin_amdgcn_permlane16_swap(r0[0], r0[1], false, false);  // {out0, out2}
  auto s1 = __builtin_amdgcn_permlane16_swap(r1[0], r1[1], false, false);  // {out1, out3}
  union { unsigned u[4]; bf16x8 v; } r;
  r.u[0] = s0[0];
  r.u[1] = s1[0];
  r.u[2] = s0[1];
  r.u[3] = s1[1];
  return r.v;
}

// ---------------- fused cast fp32 -> bf16 for x + 4 weights ----------------
static constexpr int NX4 = (2 * S * D) / 4;   // 1572864
static constexpr int NW4 = (D * D) / 4;       // 147456
__global__ void castall(const float* __restrict__ x,  const float* __restrict__ wq,
                        const float* __restrict__ wk, const float* __restrict__ wv,
                        const float* __restrict__ wo,
                        u16* __restrict__ xb,  u16* __restrict__ wqb,
                        u16* __restrict__ wkb, u16* __restrict__ wvb,
                        u16* __restrict__ wob, unsigned* __restrict__ ctr){
  if (blockIdx.x == 0 && threadIdx.x == 0) *ctr = 0u;   // reset attn work queue (stream-ordered)
  int i = blockIdx.x * 256 + threadIdx.x;
  const float* s; u16* d; int off;
  if (i < NX4) { s = x; d = xb; off = i; }
  else {
    int j = i - NX4; int wsel = j / NW4; off = j - wsel * NW4;
    if (wsel >= 4) return;
    s = (wsel == 0) ? wq : (wsel == 1) ? wk : (wsel == 2) ? wv : wo;
    d = (wsel == 0) ? wqb : (wsel == 1) ? wkb : (wsel == 2) ? wvb : wob;
  }
  float4 v = ((const float4*)s)[off];
  uint2 o;
  o.x = (unsigned)f2b(v.x) | ((unsigned)f2b(v.y) << 16);
  o.y = (unsigned)f2b(v.z) | ((unsigned)f2b(v.w) << 16);
  ((uint2*)d)[off] = o;
}

// ---------------- QKV GEMM (m97 pattern): BK=64, global_load_lds staging, XOR-swizzled LDS.
__global__ __launch_bounds__(256, 2) void qkv_gemm(
    const u16* __restrict__ xb, const u16* __restrict__ wq, const u16* __restrict__ wk,
    const u16* __restrict__ wv, u16* __restrict__ Qb, u16* __restrict__ Kb, u16* __restrict__ Vt)
{
  __shared__ __align__(16) u16 As[128 * 64];
  __shared__ __align__(16) u16 Bs[128 * 64];
  const int t = threadIdx.x;
  const int mblk = blockIdx.x, nblk = blockIdx.y, z = blockIdx.z;
  const u16* W = (z == 0) ? wq : (z == 1) ? wk : wv;
  const int w = t >> 6, lane = t & 63, quad = lane >> 4, l16 = lane & 15;
  const int wr = w >> 1, wc = w & 1;
  const int l7 = l16 & 7;

  f32x4 acc[4][4];
  #pragma unroll
  for (int i = 0; i < 4; i++)
    #pragma unroll
    for (int j = 0; j < 4; j++) acc[i][j] = (f32x4){0.f, 0.f, 0.f, 0.f};

  int srow[4], schk[4];
  #pragma unroll
  for (int i = 0; i < 4; i++) {
    int s = i * 256 + t;
    srow[i] = s >> 3;
    schk[i] = (s & 7) ^ (srow[i] & 7);
  }
  const u16* gA = xb + (size_t)(mblk * 128) * D;
  const u16* gB = W  + (size_t)(nblk * 128) * D;

  for (int k0 = 0; k0 < D; k0 += 64) {
    __syncthreads();
    #pragma unroll
    for (int i = 0; i < 4; i++) {
      int s = i * 256 + t;
      cp16(gA + (size_t)srow[i] * D + k0 + schk[i] * 8, As + s * 8);
      cp16(gB + (size_t)srow[i] * D + k0 + schk[i] * 8, Bs + s * 8);
    }
    __syncthreads();
    #pragma unroll
    for (int j = 0; j < 2; j++) {
      bf16x8 af[4], bfr[4];
      #pragma unroll
      for (int mt = 0; mt < 4; mt++)
        af[mt]  = *(const bf16x8*)(As + (wr * 64 + mt * 16 + l16) * 64 + ((j * 4 + quad) ^ l7) * 8);
      #pragma unroll
      for (int nt = 0; nt < 4; nt++)
        bfr[nt] = *(const bf16x8*)(Bs + (wc * 64 + nt * 16 + l16) * 64 + ((j * 4 + quad) ^ l7) * 8);
      #pragma unroll
      for (int mt = 0; mt < 4; mt++)
        #pragma unroll
        for (int nt = 0; nt < 4; nt++)
          acc[mt][nt] = MFMA(af[mt], bfr[nt], acc[mt][nt]);
    }
  }

  const float qscale = 0.18033688011112042f;  // 0.125 * log2(e)
  #pragma unroll
  for (int mt = 0; mt < 4; mt++) {
    int m0 = mblk * 128 + wr * 64 + mt * 16 + quad * 4;
    #pragma unroll
    for (int nt = 0; nt < 4; nt++) {
      int n = nblk * 128 + wc * 64 + nt * 16 + l16;
      int h = n >> 6, hd = n & 63;
      if (z == 2) {
        int b = m0 >> 12, s0 = m0 & 4095;
        u16* p = Vt + (((size_t)(b * H + h) * HD + hd)) * S + s0;
        uint2 pk;
        pk.x = (unsigned)f2b(acc[mt][nt][0]) | ((unsigned)f2b(acc[mt][nt][1]) << 16);
        pk.y = (unsigned)f2b(acc[mt][nt][2]) | ((unsigned)f2b(acc[mt][nt][3]) << 16);
        *(uint2*)p = pk;
      } else {
        u16* dst = (z == 0) ? Qb : Kb;
        float sc = (z == 0) ? qscale : 1.0f;
        #pragma unroll
        for (int r = 0; r < 4; r++) {
          int m = m0 + r; int b = m >> 12, s = m & 4095;
          dst[((size_t)(b * H + h) * S + s) * HD + hd] = f2b(acc[mt][nt][r] * sc);
        }
      }
    }
  }
}

// ---------------- flash attention: persistent blocks + dynamic queue + dbuf K/V ----------------
// R3 post-mortem: 768-block triangular grid -> occupancy decays from 37% to ~0 as short
// qtiles finish; makespan dominated by qtile-31 blocks running nearly alone (occ avg 17%,
// all structures land 85-94us). R4: 512 PERSISTENT blocks (2/CU at 64.6KB LDS) pull
// (bh,qtile) units longest-first off a global atomic counter -> sustained ~2 blocks/CU and
// a tail of 1-iter units. Double-buffered K/V DMA (R2 pattern) hides staging under compute.
// Wave split unchanged: 2x2 of 64q x 64k, in-register P^T via permlane transpose.
__global__ __launch_bounds__(256, 2) void attn(
    const u16* __restrict__ Qb, const u16* __restrict__ Kb,
    const u16* __restrict__ Vt, u16* __restrict__ ctx, unsigned* __restrict__ ctr)
{
  __shared__ __align__(16) u16 Ks[2][128 * 64];   // K tile [key][hd], chunk c at c^(key&7)   : 2x16 KB
  __shared__ __align__(16) u16 Vts[2][64 * 128];  // V^T tile [hd][key], chunk c at c^(hd&15) : 2x16 KB
  __shared__ float Lbuf[2][4][16];                // lsum exchange: [wq][qt][l16]
  __shared__ unsigned s_unit;
  const int t = threadIdx.x, w = t >> 6, lane = t & 63, quad = lane >> 4, l16 = lane & 15;
  const int l7 = l16 & 7;
  const int wq = w >> 1, wk = w & 1;              // query-half, key-half of this wave

  // DMA slot descriptors (unit-independent).
  // K: slot s -> key s>>3, chunk (s&7)^(key&7).  V: slot s -> hd s>>4, chunk (s&15)^(hd&15).
  int krow[4], kchk[4], vrow[4], vchk[4];
  #pragma unroll
  for (int i = 0; i < 4; i++) {
    int s = i * 256 + t;
    krow[i] = s >> 3;  kchk[i] = (s & 7)  ^ (krow[i] & 7);
    vrow[i] = s >> 4;  vchk[i] = (s & 15) ^ (vrow[i] & 15);
  }

  for (;;) {
    if (t == 0) s_unit = atomicAdd(ctr, 1u);
    __syncthreads();                              // broadcast unit; also fences prior unit's LDS reads
    const unsigned u = s_unit;
    if (u >= NUNITS) break;
    const int bh    = (int)(u % 24u);
    const int qtile = 31 - (int)(u / 24u);        // longest-first
    const int q0 = qtile * 128;
    const u16* Qh = Qb + (size_t)bh * S * HD;
    const u16* Kh = Kb + (size_t)bh * S * HD;
    const u16* Vh = Vt + (size_t)bh * S * HD;     // [64][4096]
    const int b = bh / H, h = bh % H;

    // Q fragments (B-operand): lane holds Q[q0+wq*64+qt*16+l16][ksh*32+quad*8 ..+7]
    bf16x8 qf[4][2];
    #pragma unroll
    for (int qt = 0; qt < 4; qt++)
      #pragma unroll
      for (int ksh = 0; ksh < 2; ksh++)
        qf[qt][ksh] = *(const bf16x8*)(Qh + (size_t)(q0 + wq * 64 + qt * 16 + l16) * HD + ksh * 32 + quad * 8);

    // O^T acc: row=hd (co*16+quad*4+r), col=query (qt*16+l16); partial over this wave's keys
    f32x4 ao[4][4];
    #pragma unroll
    for (int qt = 0; qt < 4; qt++)
      #pragma unroll
      for (int co = 0; co < 4; co++) ao[qt][co] = (f32x4){0.f, 0.f, 0.f, 0.f};
    float lsum[4] = {0.f, 0.f, 0.f, 0.f};

    // prologue: stage first tile into buffer 0
    #pragma unroll
    for (int i = 0; i < 4; i++) {
      int s = i * 256 + t;
      cp16(Kh + (size_t)krow[i] * HD + kchk[i] * 8, &Ks[0][0] + s * 8);
      cp16(Vh + (size_t)vrow[i] * S + vchk[i] * 8,  &Vts[0][0] + s * 8);
    }

    int cur = 0;
    for (int kv0 = 0; kv0 <= q0; kv0 += 128) {
      const bool diag    = (kv0 == q0);
      const bool skipall = diag && (wk > wq);     // keys entirely above queries
      const bool mdiag   = diag && (wk == wq);    // element-mask region

      // barrier: buf[cur]'s DMA drained (vmcnt 0 at syncthreads) AND
      //          all waves done reading buf[cur^1] from previous iter
      __syncthreads();

      if (!diag) {                                // stage NEXT tile into the other buffer
        const int kn = kv0 + 128;
        #pragma unroll
        for (int i = 0; i < 4; i++) {
          int s = i * 256 + t;
          cp16(Kh + (size_t)(kn + krow[i]) * HD + kchk[i] * 8, &Ks[cur ^ 1][0] + s * 8);
          cp16(Vh + (size_t)vrow[i] * S + kn + vchk[i] * 8,    &Vts[cur ^ 1][0] + s * 8);
        }
      }

      if (!skipall) {
        const u16* Kc = &Ks[cur][0];
        const u16* Vc = &Vts[cur][0];
        #pragma unroll
        for (int g = 0; g < 2; g++) {             // 32-key groups within this wave's 64 keys
          unsigned pA[4][2], pB[4][2];            // [qt][ktL]: packed bf16 pairs
          #pragma unroll
          for (int ktL = 0; ktL < 2; ktL++) {
            const int kt  = g * 2 + ktL;          // 16-key tile index within 64
            const int krw = wk * 64 + kt * 16 + l16;
            bf16x8 kf0 = *(const bf16x8*)(Kc + krw * 64 + ((0 + quad) ^ l7) * 8);
            bf16x8 kf1 = *(const bf16x8*)(Kc + krw * 64 + ((4 + quad) ^ l7) * 8);
            #pragma unroll
            for (int qt = 0; qt < 4; qt++) {
              f32x4 s0 = (f32x4){0.f, 0.f, 0.f, 0.f};
              s0 = MFMA(kf0, qf[qt][0], s0);
              s0 = MFMA(kf1, qf[qt][1], s0);
              if (mdiag) {
                // key_rel = kt*16+quad*4+r, query_rel = qt*16+l16; mask key>query
                const int qoff = (qt - kt) * 16 + l16;
                #pragma unroll
                for (int r = 0; r < 4; r++)
                  s0[r] = (quad * 4 + r > qoff) ? -1e30f : s0[r];
              }
              float p0 = __builtin_amdgcn_exp2f(s0[0]);
              float p1 = __builtin_amdgcn_exp2f(s0[1]);
              float p2 = __builtin_amdgcn_exp2f(s0[2]);
              float p3 = __builtin_amdgcn_exp2f(s0[3]);
              lsum[qt] += (p0 + p1) + (p2 + p3);
              pA[qt][ktL] = pack_bf16_trunc(p0, p1);
              pB[qt][ktL] = pack_bf16_trunc(p2, p3);
            }
          }
          // in-register P^T fragments for this 32-key group
          bf16x8 pf[4];
          #pragma unroll
          for (int qt = 0; qt < 4; qt++)
            pf[qt] = quad_transpose(pA[qt][0], pB[qt][0], pA[qt][1], pB[qt][1]);
          // O^T += V^T P^T
          #pragma unroll
          for (int co = 0; co < 4; co++) {
            const int vrw = co * 16 + l16;
            bf16x8 vf = *(const bf16x8*)(Vc + vrw * 128 + ((wk * 8 + g * 4 + quad) ^ (vrw & 15)) * 8);
            #pragma unroll
            for (int qt = 0; qt < 4; qt++)
              ao[qt][co] = MFMA(vf, pf[qt], ao[qt][co]);
          }
        }
      }
      cur ^= 1;
    }

    // ---- epilogue: quad-reduce lsum, then cross-wave (wk) reduction of O and lsum ----
    #pragma unroll
    for (int qt = 0; qt < 4; qt++) {
      float v = lsum[qt];
      v += __shfl_xor(v, 16, 64);
      v += __shfl_xor(v, 32, 64);
      lsum[qt] = v;
    }

    __syncthreads();                              // all loop-phase LDS reads done
    float* red = wq ? (float*)&Vts[0][0] : (float*)&Ks[0][0];   // 16KB scratch per query-half pair
    if (wk == 1) {
      #pragma unroll
      for (int qt = 0; qt < 4; qt++)
        #pragma unroll
        for (int co = 0; co < 4; co++)
          *(f32x4*)(red + ((qt * 4 + co) * 64 + lane) * 4) = ao[qt][co];
      if (lane < 16) {
        #pragma unroll
        for (int qt = 0; qt < 4; qt++) Lbuf[wq][qt][lane] = lsum[qt];
      }
    }
    __syncthreads();
    if (wk == 0) {
      #pragma unroll
      for (int qt = 0; qt < 4; qt++) {
        float tot = lsum[qt] + Lbuf[wq][qt][l16];
        float inv = 1.0f / tot;
        int token = b * S + q0 + wq * 64 + qt * 16 + l16;
        #pragma unroll
        for (int co = 0; co < 4; co++) {
          f32x4 pr = *(const f32x4*)(red + ((qt * 4 + co) * 64 + lane) * 4);
          f32x4 sv = ao[qt][co] + pr;
          uint2 pk;
          pk.x = (unsigned)f2b(sv[0] * inv) | ((unsigned)f2b(sv[1] * inv) << 16);
          pk.y = (unsigned)f2b(sv[2] * inv) | ((unsigned)f2b(sv[3] * inv) << 16);
          *(uint2*)(ctx + (size_t)token * D + h * HD + co * 16 + quad * 4) = pk;
        }
      }
    }
    // next unit: top-of-loop __syncthreads fences red reads before restaging buf0
  }
}

// ---------------- output projection (m97 pattern): ctx[8192,768] x Wo^T + bias -> fp32 out
__global__ __launch_bounds__(256, 2) void out_gemm(
    const u16* __restrict__ ctx, const u16* __restrict__ wo,
    const float* __restrict__ bias, float* __restrict__ out)
{
  __shared__ __align__(16) u16 As[128 * 64];
  __shared__ __align__(16) u16 Bs[128 * 64];
  const int t = threadIdx.x;
  const int mblk = blockIdx.x, nblk = blockIdx.y;
  const int w = t >> 6, lane = t & 63, quad = lane >> 4, l16 = lane & 15;
  const int wr = w >> 1, wc = w & 1;
  const int l7 = l16 & 7;

  f32x4 acc[4][4];
  #pragma unroll
  for (int i = 0; i < 4; i++)
    #pragma unroll
    for (int j = 0; j < 4; j++) acc[i][j] = (f32x4){0.f, 0.f, 0.f, 0.f};

  int srow[4], schk[4];
  #pragma unroll
  for (int i = 0; i < 4; i++) {
    int s = i * 256 + t;
    srow[i] = s >> 3;
    schk[i] = (s & 7) ^ (srow[i] & 7);
  }
  const u16* gA = ctx + (size_t)(mblk * 128) * D;
  const u16* gB = wo  + (size_t)(nblk * 128) * D;

  for (int k0 = 0; k0 < D; k0 += 64) {
    __syncthreads();
    #pragma unroll
    for (int i = 0; i < 4; i++) {
      int s = i * 256 + t;
      cp16(gA + (size_t)srow[i] * D + k0 + schk[i] * 8, As + s * 8);
      cp16(gB + (size_t)srow[i] * D + k0 + schk[i] * 8, Bs + s * 8);
    }
    __syncthreads();
    #pragma unroll
    for (int j = 0; j < 2; j++) {
      bf16x8 af[4], bfr[4];
      #pragma unroll
      for (int mt = 0; mt < 4; mt++)
        af[mt]  = *(const bf16x8*)(As + (wr * 64 + mt * 16 + l16) * 64 + ((j * 4 + quad) ^ l7) * 8);
      #pragma unroll
      for (int nt = 0; nt < 4; nt++)
        bfr[nt] = *(const bf16x8*)(Bs + (wc * 64 + nt * 16 + l16) * 64 + ((j * 4 + quad) ^ l7) * 8);
      #pragma unroll
      for (int mt = 0; mt < 4; mt++)
        #pragma unroll
        for (int nt = 0; nt < 4; nt++)
          acc[mt][nt] = MFMA(af[mt], bfr[nt], acc[mt][nt]);
    }
  }

  #pragma unroll
  for (int mt = 0; mt < 4; mt++) {
    int m0 = mblk * 128 + wr * 64 + mt * 16 + quad * 4;
    #pragma unroll
    for (int nt = 0; nt < 4; nt++) {
      int n = nblk * 128 + wc * 64 + nt * 16 + l16;
      float bv = bias[n];
      #pragma unroll
      for (int r = 0; r < 4; r++)
        out[(size_t)(m0 + r) * D + n] = acc[mt][nt][r] + bv;
    }
  }
}

// ---------------- host launch ----------------
extern "C" void kernel_launch(void* const* d_in, const int* in_sizes, int n_in,
                              void* d_out, int out_size, void* d_ws, size_t ws_size,
                              hipStream_t stream) {
  const float* x    = (const float*)d_in[0];
  const float* wq   = (const float*)d_in[1];
  const float* wk   = (const float*)d_in[2];
  const float* wv   = (const float*)d_in[3];
  const float* wo   = (const float*)d_in[4];
  const float* bo   = (const float*)d_in[5];
  float* out = (float*)d_out;

  u16* ws = (u16*)d_ws;
  const size_t NX = (size_t)2 * S * D;      // 6291456
  const size_t NW = (size_t)D * D;          // 589824
  u16* xb  = ws;                // [8192][768]; reused as ctx after qkv_gemm consumes it
  u16* wqb = ws + NX;
  u16* wkb = wqb + NW;
  u16* wvb = wkb + NW;
  u16* wob = wvb + NW;
  u16* Qb  = wob + NW;          // [2][12][4096][64] bf16 (pre-scaled by 0.125*log2e)
  u16* Kb  = Qb + NX;           // bf16
  u16* Vt  = Kb + NX;           // [2][12][64][4096] bf16
  u16* ctx = xb;
  unsigned* ctr = (unsigned*)(Vt + NX);     // attn dynamic work-queue counter (4B)

  const int total4 = NX4 + 4 * NW4;
  castall<<<(total4 + 255) / 256, 256, 0, stream>>>(x, wq, wk, wv, wo, xb, wqb, wkb, wvb, wob, ctr);

  qkv_gemm<<<dim3(64, 6, 3), 256, 0, stream>>>(xb, wqb, wkb, wvb, Qb, Kb, Vt);
  attn<<<dim3(512), 256, 0, stream>>>(Qb, Kb, Vt, ctx, ctr);
  out_gemm<<<dim3(64, 6), 256, 0, stream>>>(ctx, wob, bo, out);
}

// Round 5
// 217.441 us; speedup vs baseline: 1.0705x; 1.0705x over previous
//
#include <hip/hip_runtime.h>
#include <stdint.h>

typedef unsigned short u16;
typedef __attribute__((ext_vector_type(8))) short bf16x8;
typedef __attribute__((ext_vector_type(4))) float f32x4;

#define MFMA(a,b,c) __builtin_amdgcn_mfma_f32_16x16x32_bf16((a),(b),(c),0,0,0)

static constexpr int S  = 4096;
static constexpr int D  = 768;
static constexpr int H  = 12;
static constexpr int HD = 64;

// float -> bf16 round-nearest-even
__device__ __forceinline__ u16 f2b(float f){
  union { float f; unsigned u; } v; v.f = f;
  unsigned r = (v.u + 0x7fffu + ((v.u >> 16) & 1u)) >> 16;
  return (u16)r;
}

// pack 2 floats -> 2 bf16 (truncation) in ONE v_perm_b32
__device__ __forceinline__ unsigned pack_bf16_trunc(float a, float b){
  return __builtin_amdgcn_perm(__float_as_uint(b), __float_as_uint(a), 0x07060302u);
}

// async global->LDS 16B per lane (DMA path, no VGPR round-trip)
__device__ __forceinline__ void cp16(const u16* g, u16* l){
  __builtin_amdgcn_global_load_lds(
      (const __attribute__((address_space(1))) unsigned int*)g,
      (__attribute__((address_space(3))) unsigned int*)l, 16, 0, 0);
}

// 4-lane (quad) butterfly transpose via gfx950 permlane swaps (4 VALU instrs).
// Input M[c]: keys ktL*16 + quad*4 + {0,1 | 2,3} (32-key group) packed 2-bf16/u32.
// Output: bf16x8 P fragment: lane quad holds keys quad*8 .. quad*8+7 in order.
__device__ __forceinline__ bf16x8 quad_transpose(unsigned M0, unsigned M1,
                                                 unsigned M2, unsigned M3){
  auto r0 = __builtin_amdgcn_permlane32_swap(M0, M2, false, false);  // {A0, A2}
  auto r1 = __builtin_amdgcn_permlane32_swap(M1, M3, false, false);  // {A1, A3}
  auto s0 = __builtin_amdgcn_permlane16_swap(r0[0], r0[1], false, false);  // {out0, out2}
  auto s1 = __builtin_amdgcn_permlane16_swap(r1[0], r1[1], false, false);  // {out1, out3}
  union { unsigned u[4]; bf16x8 v; } r;
  r.u[0] = s0[0];
  r.u[1] = s1[0];
  r.u[2] = s0[1];
  r.u[3] = s1[1];
  return r.v;
}

// ---------------- fused cast fp32 -> bf16 for x + 4 weights ----------------
static constexpr int NX4 = (2 * S * D) / 4;   // 1572864
static constexpr int NW4 = (D * D) / 4;       // 147456
__global__ void castall(const float* __restrict__ x,  const float* __restrict__ wq,
                        const float* __restrict__ wk, const float* __restrict__ wv,
                        const float* __restrict__ wo,
                        u16* __restrict__ xb,  u16* __restrict__ wqb,
                        u16* __restrict__ wkb, u16* __restrict__ wvb,
                        u16* __restrict__ wob){
  int i = blockIdx.x * 256 + threadIdx.x;
  const float* s; u16* d; int off;
  if (i < NX4) { s = x; d = xb; off = i; }
  else {
    int j = i - NX4; int wsel = j / NW4; off = j - wsel * NW4;
    if (wsel >= 4) return;
    s = (wsel == 0) ? wq : (wsel == 1) ? wk : (wsel == 2) ? wv : wo;
    d = (wsel == 0) ? wqb : (wsel == 1) ? wkb : (wsel == 2) ? wvb : wob;
  }
  float4 v = ((const float4*)s)[off];
  uint2 o;
  o.x = (unsigned)f2b(v.x) | ((unsigned)f2b(v.y) << 16);
  o.y = (unsigned)f2b(v.z) | ((unsigned)f2b(v.w) << 16);
  ((uint2*)d)[off] = o;
}

// ---------------- QKV GEMM (m97 pattern): BK=64, global_load_lds staging, XOR-swizzled LDS.
__global__ __launch_bounds__(256, 2) void qkv_gemm(
    const u16* __restrict__ xb, const u16* __restrict__ wq, const u16* __restrict__ wk,
    const u16* __restrict__ wv, u16* __restrict__ Qb, u16* __restrict__ Kb, u16* __restrict__ Vt)
{
  __shared__ __align__(16) u16 As[128 * 64];
  __shared__ __align__(16) u16 Bs[128 * 64];
  const int t = threadIdx.x;
  const int mblk = blockIdx.x, nblk = blockIdx.y, z = blockIdx.z;
  const u16* W = (z == 0) ? wq : (z == 1) ? wk : wv;
  const int w = t >> 6, lane = t & 63, quad = lane >> 4, l16 = lane & 15;
  const int wr = w >> 1, wc = w & 1;
  const int l7 = l16 & 7;

  f32x4 acc[4][4];
  #pragma unroll
  for (int i = 0; i < 4; i++)
    #pragma unroll
    for (int j = 0; j < 4; j++) acc[i][j] = (f32x4){0.f, 0.f, 0.f, 0.f};

  int srow[4], schk[4];
  #pragma unroll
  for (int i = 0; i < 4; i++) {
    int s = i * 256 + t;
    srow[i] = s >> 3;
    schk[i] = (s & 7) ^ (srow[i] & 7);
  }
  const u16* gA = xb + (size_t)(mblk * 128) * D;
  const u16* gB = W  + (size_t)(nblk * 128) * D;

  for (int k0 = 0; k0 < D; k0 += 64) {
    __syncthreads();
    #pragma unroll
    for (int i = 0; i < 4; i++) {
      int s = i * 256 + t;
      cp16(gA + (size_t)srow[i] * D + k0 + schk[i] * 8, As + s * 8);
      cp16(gB + (size_t)srow[i] * D + k0 + schk[i] * 8, Bs + s * 8);
    }
    __syncthreads();
    #pragma unroll
    for (int j = 0; j < 2; j++) {
      bf16x8 af[4], bfr[4];
      #pragma unroll
      for (int mt = 0; mt < 4; mt++)
        af[mt]  = *(const bf16x8*)(As + (wr * 64 + mt * 16 + l16) * 64 + ((j * 4 + quad) ^ l7) * 8);
      #pragma unroll
      for (int nt = 0; nt < 4; nt++)
        bfr[nt] = *(const bf16x8*)(Bs + (wc * 64 + nt * 16 + l16) * 64 + ((j * 4 + quad) ^ l7) * 8);
      #pragma unroll
      for (int mt = 0; mt < 4; mt++)
        #pragma unroll
        for (int nt = 0; nt < 4; nt++)
          acc[mt][nt] = MFMA(af[mt], bfr[nt], acc[mt][nt]);
    }
  }

  const float qscale = 0.18033688011112042f;  // 0.125 * log2(e)
  #pragma unroll
  for (int mt = 0; mt < 4; mt++) {
    int m0 = mblk * 128 + wr * 64 + mt * 16 + quad * 4;
    #pragma unroll
    for (int nt = 0; nt < 4; nt++) {
      int n = nblk * 128 + wc * 64 + nt * 16 + l16;
      int h = n >> 6, hd = n & 63;
      if (z == 2) {
        int b = m0 >> 12, s0 = m0 & 4095;
        u16* p = Vt + (((size_t)(b * H + h) * HD + hd)) * S + s0;
        uint2 pk;
        pk.x = (unsigned)f2b(acc[mt][nt][0]) | ((unsigned)f2b(acc[mt][nt][1]) << 16);
        pk.y = (unsigned)f2b(acc[mt][nt][2]) | ((unsigned)f2b(acc[mt][nt][3]) << 16);
        *(uint2*)p = pk;
      } else {
        u16* dst = (z == 0) ? Qb : Kb;
        float sc = (z == 0) ? qscale : 1.0f;
        #pragma unroll
        for (int r = 0; r < 4; r++) {
          int m = m0 + r; int b = m >> 12, s = m & 4095;
          dst[((size_t)(b * H + h) * S + s) * HD + hd] = f2b(acc[mt][nt][r] * sc);
        }
      }
    }
  }
}

// ---------------- flash attention, 2x2 wave split (64q x 64k per wave) ----------------
// R4 post-mortem: dynamic queue destroyed bh->L2 locality (FETCH 20->128MB) and dbuf LDS
// halved residency; net loss. R3 analysis: all 768 blocks are co-resident (33KB LDS,
// 112 VGPR -> 3/CU); the cost is per-CU work imbalance (round-robin CU triples sum 33..64
// kv-iters). R5: keep R3's kernel EXACTLY; remap blockIdx -> (bh,qtile) with a per-XCD
// 3-round snake so each CU triple {j, 63-j, 64+j} sums 45..54, and each XCD touches only
// 3 bhs (3MB K/V < 4MB L2). Mapping is a bijection: correctness independent of dispatcher.
// grid: 768 blocks, 1D.
__global__ __launch_bounds__(256, 2) void attn(
    const u16* __restrict__ Qb, const u16* __restrict__ Kb,
    const u16* __restrict__ Vt, u16* __restrict__ ctx)
{
  __shared__ __align__(16) u16 Ks[128 * 64];    // K tile [key][hd], chunk c at c^(key&7)   : 16 KB
  __shared__ __align__(16) u16 Vts[64 * 128];   // V^T tile [hd][key], chunk c at c^(hd&15) : 16 KB
  __shared__ float Lbuf[2][4][16];              // lsum exchange: [wq][qt][l16]
  const int t = threadIdx.x, w = t >> 6, lane = t & 63, quad = lane >> 4, l16 = lane & 15;
  const int l7 = l16 & 7;
  const int wq = w >> 1, wk = w & 1;            // query-half, key-half of this wave

  // ---- balanced XCD-local unit mapping ----
  // p -> xcd = p&7 (HW round-robin heuristic), loc = p>>3 in [0,96).
  // XCD's units: 3 bhs {xcd, xcd+8, xcd+16} x 32 qtiles, sorted longest-first:
  //   U[u]: qtile = 31 - u/3, bh = xcd + 8*(u%3).
  // 3-round snake: round r = loc>>5, j = loc&31 -> u = {j, 63-j, 64+j}.
  // CU triple {p, p+256, p+512} = same j, rounds 0..2 -> work sums 45..54 (vs 33..64).
  const int p   = (int)blockIdx.x;
  const int xcd = p & 7;
  const int loc = p >> 3;
  const int r_  = loc >> 5, j_ = loc & 31;
  const int u   = (r_ == 0) ? j_ : (r_ == 1) ? (63 - j_) : (64 + j_);
  const int qtile = 31 - u / 3;
  const int bh    = xcd + 8 * (u % 3);

  const int q0 = qtile * 128;
  const u16* Qh = Qb + (size_t)bh * S * HD;
  const u16* Kh = Kb + (size_t)bh * S * HD;
  const u16* Vh = Vt + (size_t)bh * S * HD;     // [64][4096]
  const int b = bh / H, h = bh % H;

  // Q fragments (B-operand): lane holds Q[q0+wq*64+qt*16+l16][ksh*32+quad*8 ..+7]
  bf16x8 qf[4][2];
  #pragma unroll
  for (int qt = 0; qt < 4; qt++)
    #pragma unroll
    for (int ksh = 0; ksh < 2; ksh++)
      qf[qt][ksh] = *(const bf16x8*)(Qh + (size_t)(q0 + wq * 64 + qt * 16 + l16) * HD + ksh * 32 + quad * 8);

  // O^T acc: row=hd (co*16+quad*4+r), col=query (qt*16+l16); partial over this wave's keys
  f32x4 ao[4][4];
  #pragma unroll
  for (int qt = 0; qt < 4; qt++)
    #pragma unroll
    for (int co = 0; co < 4; co++) ao[qt][co] = (f32x4){0.f, 0.f, 0.f, 0.f};
  float lsum[4] = {0.f, 0.f, 0.f, 0.f};         // per-lane partial denominators, query qt*16+l16

  // DMA slot descriptors. K: slot s -> key s>>3, chunk (s&7)^(key&7).
  //                       V: slot s -> hd  s>>4, chunk (s&15)^(hd&15).
  int krow[4], kchk[4], vrow[4], vchk[4];
  #pragma unroll
  for (int i = 0; i < 4; i++) {
    int s = i * 256 + t;
    krow[i] = s >> 3;  kchk[i] = (s & 7)  ^ (krow[i] & 7);
    vrow[i] = s >> 4;  vchk[i] = (s & 15) ^ (vrow[i] & 15);
  }

  for (int kv0 = 0; kv0 <= q0; kv0 += 128) {
    const bool diag    = (kv0 == q0);
    const bool skipall = diag && (wk > wq);     // keys entirely above queries
    const bool mdiag   = diag && (wk == wq);    // element-mask region

    __syncthreads();   // prior iter's LDS reads complete
    #pragma unroll
    for (int i = 0; i < 4; i++) {
      int s = i * 256 + t;
      cp16(Kh + (size_t)(kv0 + krow[i]) * HD + kchk[i] * 8, Ks + s * 8);
      cp16(Vh + (size_t)vrow[i] * S + kv0 + vchk[i] * 8,    Vts + s * 8);
    }
    __syncthreads();   // DMA arrived (vmcnt drained at barrier)

    if (!skipall) {
      #pragma unroll
      for (int g = 0; g < 2; g++) {             // 32-key groups within this wave's 64 keys
        unsigned pA[4][2], pB[4][2];            // [qt][ktL]: packed bf16 pairs
        #pragma unroll
        for (int ktL = 0; ktL < 2; ktL++) {
          const int kt  = g * 2 + ktL;          // 16-key tile index within 64
          const int krw = wk * 64 + kt * 16 + l16;
          bf16x8 kf0 = *(const bf16x8*)(Ks + krw * 64 + ((0 + quad) ^ l7) * 8);
          bf16x8 kf1 = *(const bf16x8*)(Ks + krw * 64 + ((4 + quad) ^ l7) * 8);
          #pragma unroll
          for (int qt = 0; qt < 4; qt++) {
            f32x4 s0 = (f32x4){0.f, 0.f, 0.f, 0.f};
            s0 = MFMA(kf0, qf[qt][0], s0);
            s0 = MFMA(kf1, qf[qt][1], s0);
            if (mdiag) {
              // key_rel = kt*16+quad*4+r, query_rel = qt*16+l16; mask key>query
              const int qoff = (qt - kt) * 16 + l16;
              #pragma unroll
              for (int r = 0; r < 4; r++)
                s0[r] = (quad * 4 + r > qoff) ? -1e30f : s0[r];
            }
            float p0 = __builtin_amdgcn_exp2f(s0[0]);
            float p1 = __builtin_amdgcn_exp2f(s0[1]);
            float p2 = __builtin_amdgcn_exp2f(s0[2]);
            float p3 = __builtin_amdgcn_exp2f(s0[3]);
            lsum[qt] += (p0 + p1) + (p2 + p3);
            pA[qt][ktL] = pack_bf16_trunc(p0, p1);
            pB[qt][ktL] = pack_bf16_trunc(p2, p3);
          }
        }
        // in-register P^T fragments for this 32-key group
        bf16x8 pf[4];
        #pragma unroll
        for (int qt = 0; qt < 4; qt++)
          pf[qt] = quad_transpose(pA[qt][0], pB[qt][0], pA[qt][1], pB[qt][1]);
        // O^T += V^T P^T
        #pragma unroll
        for (int co = 0; co < 4; co++) {
          const int vrw = co * 16 + l16;
          bf16x8 vf = *(const bf16x8*)(Vts + vrw * 128 + ((wk * 8 + g * 4 + quad) ^ (vrw & 15)) * 8);
          #pragma unroll
          for (int qt = 0; qt < 4; qt++)
            ao[qt][co] = MFMA(vf, pf[qt], ao[qt][co]);
        }
      }
    }
  }

  // ---- epilogue: quad-reduce lsum, then cross-wave (wk) reduction of O and lsum ----
  #pragma unroll
  for (int qt = 0; qt < 4; qt++) {
    float v = lsum[qt];
    v += __shfl_xor(v, 16, 64);
    v += __shfl_xor(v, 32, 64);
    lsum[qt] = v;
  }

  __syncthreads();                              // all loop-phase LDS reads done
  float* red = wq ? (float*)Vts : (float*)Ks;   // 16KB scratch per query-half pair
  if (wk == 1) {
    #pragma unroll
    for (int qt = 0; qt < 4; qt++)
      #pragma unroll
      for (int co = 0; co < 4; co++)
        *(f32x4*)(red + ((qt * 4 + co) * 64 + lane) * 4) = ao[qt][co];
    if (lane < 16) {
      #pragma unroll
      for (int qt = 0; qt < 4; qt++) Lbuf[wq][qt][lane] = lsum[qt];
    }
  }
  __syncthreads();
  if (wk == 0) {
    #pragma unroll
    for (int qt = 0; qt < 4; qt++) {
      float tot = lsum[qt] + Lbuf[wq][qt][l16];
      float inv = 1.0f / tot;
      int token = b * S + q0 + wq * 64 + qt * 16 + l16;
      #pragma unroll
      for (int co = 0; co < 4; co++) {
        f32x4 pr = *(const f32x4*)(red + ((qt * 4 + co) * 64 + lane) * 4);
        f32x4 sv = ao[qt][co] + pr;
        uint2 pk;
        pk.x = (unsigned)f2b(sv[0] * inv) | ((unsigned)f2b(sv[1] * inv) << 16);
        pk.y = (unsigned)f2b(sv[2] * inv) | ((unsigned)f2b(sv[3] * inv) << 16);
        *(uint2*)(ctx + (size_t)token * D + h * HD + co * 16 + quad * 4) = pk;
      }
    }
  }
}

// ---------------- output projection (m97 pattern): ctx[8192,768] x Wo^T + bias -> fp32 out
__global__ __launch_bounds__(256, 2) void out_gemm(
    const u16* __restrict__ ctx, const u16* __restrict__ wo,
    const float* __restrict__ bias, float* __restrict__ out)
{
  __shared__ __align__(16) u16 As[128 * 64];
  __shared__ __align__(16) u16 Bs[128 * 64];
  const int t = threadIdx.x;
  const int mblk = blockIdx.x, nblk = blockIdx.y;
  const int w = t >> 6, lane = t & 63, quad = lane >> 4, l16 = lane & 15;
  const int wr = w >> 1, wc = w & 1;
  const int l7 = l16 & 7;

  f32x4 acc[4][4];
  #pragma unroll
  for (int i = 0; i < 4; i++)
    #pragma unroll
    for (int j = 0; j < 4; j++) acc[i][j] = (f32x4){0.f, 0.f, 0.f, 0.f};

  int srow[4], schk[4];
  #pragma unroll
  for (int i = 0; i < 4; i++) {
    int s = i * 256 + t;
    srow[i] = s >> 3;
    schk[i] = (s & 7) ^ (srow[i] & 7);
  }
  const u16* gA = ctx + (size_t)(mblk * 128) * D;
  const u16* gB = wo  + (size_t)(nblk * 128) * D;

  for (int k0 = 0; k0 < D; k0 += 64) {
    __syncthreads();
    #pragma unroll
    for (int i = 0; i < 4; i++) {
      int s = i * 256 + t;
      cp16(gA + (size_t)srow[i] * D + k0 + schk[i] * 8, As + s * 8);
      cp16(gB + (size_t)srow[i] * D + k0 + schk[i] * 8, Bs + s * 8);
    }
    __syncthreads();
    #pragma unroll
    for (int j = 0; j < 2; j++) {
      bf16x8 af[4], bfr[4];
      #pragma unroll
      for (int mt = 0; mt < 4; mt++)
        af[mt]  = *(const bf16x8*)(As + (wr * 64 + mt * 16 + l16) * 64 + ((j * 4 + quad) ^ l7) * 8);
      #pragma unroll
      for (int nt = 0; nt < 4; nt++)
        bfr[nt] = *(const bf16x8*)(Bs + (wc * 64 + nt * 16 + l16) * 64 + ((j * 4 + quad) ^ l7) * 8);
      #pragma unroll
      for (int mt = 0; mt < 4; mt++)
        #pragma unroll
        for (int nt = 0; nt < 4; nt++)
          acc[mt][nt] = MFMA(af[mt], bfr[nt], acc[mt][nt]);
    }
  }

  #pragma unroll
  for (int mt = 0; mt < 4; mt++) {
    int m0 = mblk * 128 + wr * 64 + mt * 16 + quad * 4;
    #pragma unroll
    for (int nt = 0; nt < 4; nt++) {
      int n = nblk * 128 + wc * 64 + nt * 16 + l16;
      float bv = bias[n];
      #pragma unroll
      for (int r = 0; r < 4; r++)
        out[(size_t)(m0 + r) * D + n] = acc[mt][nt][r] + bv;
    }
  }
}

// ---------------- host launch ----------------
extern "C" void kernel_launch(void* const* d_in, const int* in_sizes, int n_in,
                              void* d_out, int out_size, void* d_ws, size_t ws_size,
                              hipStream_t stream) {
  const float* x    = (const float*)d_in[0];
  const float* wq   = (const float*)d_in[1];
  const float* wk   = (const float*)d_in[2];
  const float* wv   = (const float*)d_in[3];
  const float* wo   = (const float*)d_in[4];
  const float* bo   = (const float*)d_in[5];
  float* out = (float*)d_out;

  u16* ws = (u16*)d_ws;
  const size_t NX = (size_t)2 * S * D;      // 6291456
  const size_t NW = (size_t)D * D;          // 589824
  u16* xb  = ws;                // [8192][768]; reused as ctx after qkv_gemm consumes it
  u16* wqb = ws + NX;
  u16* wkb = wqb + NW;
  u16* wvb = wkb + NW;
  u16* wob = wvb + NW;
  u16* Qb  = wob + NW;          // [2][12][4096][64] bf16 (pre-scaled by 0.125*log2e)
  u16* Kb  = Qb + NX;           // bf16
  u16* Vt  = Kb + NX;           // [2][12][64][4096] bf16
  u16* ctx = xb;

  const int total4 = NX4 + 4 * NW4;
  castall<<<(total4 + 255) / 256, 256, 0, stream>>>(x, wq, wk, wv, wo, xb, wqb, wkb, wvb, wob);

  qkv_gemm<<<dim3(64, 6, 3), 256, 0, stream>>>(xb, wqb, wkb, wvb, Qb, Kb, Vt);
  attn<<<dim3(768), 256, 0, stream>>>(Qb, Kb, Vt, ctx);
  out_gemm<<<dim3(64, 6), 256, 0, stream>>>(ctx, wob, bo, out);
}